// Round 1
// baseline (222.264 us; speedup 1.0000x reference)
//
#include <hip/hip_runtime.h>
#include <stdint.h>

typedef short v8s __attribute__((ext_vector_type(8)));
typedef float v4f __attribute__((ext_vector_type(4)));

#define KS    7
#define KPTS  9
#define OCH   128
#define CCH   128
#define NB    32
#define HW    56
#define PAD   3
#define KTOT  (KS*KS*OCH*CCH)   // 802816

#define HBLK  4
#define ROWS  10     // HBLK + 6
#define WP    72     // padded w' extent (need 70)
#define CCK   32     // c chunk staged per pass

__device__ __forceinline__ unsigned short f2bf(float f) {
  unsigned int u = __builtin_bit_cast(unsigned int, f);
  u += 0x7fffu + ((u >> 16) & 1u);
  return (unsigned short)(u >> 16);
}

__global__ void zero_kf(float* kf) {
  int i = blockIdx.x * 256 + threadIdx.x;
  if (i < KTOT) kf[i] = 0.f;
}

// One block per (c, k-point); 128 threads = o. Bilinear scatter-add with drop.
__global__ void scatter_kern(const float* __restrict__ wgt,
                             const float* __restrict__ P,
                             float* __restrict__ kf) {
  const int c = blockIdx.x, k = blockIdx.y, o = threadIdx.x;
  const float p0 = P[c*KPTS + k];
  const float p1 = P[CCH*KPTS + c*KPTS + k];
  const float ph = fminf(fmaxf(p0, -3.f), 3.f) + 3.f;
  const float pw = fminf(fmaxf(p1, -3.f), 3.f) + 3.f;
  const int ih = (int)floorf(ph), iw = (int)floorf(pw);
  const float rh = ph - (float)ih, rw = pw - (float)iw;
  const float wt = wgt[(o*CCH + c)*KPTS + k];
  const float f00 = (1.f-rh)*(1.f-rw);
  const float f01 = (1.f-rh)*rw;
  const float f10 = rh*(1.f-rw);
  const float f11 = rh*rw;
  atomicAdd(&kf[((ih*KS + iw)*OCH + o)*CCH + c], wt*f00);
  if (iw+1 < KS) atomicAdd(&kf[((ih*KS + iw+1)*OCH + o)*CCH + c], wt*f01);
  if (ih+1 < KS) atomicAdd(&kf[(((ih+1)*KS + iw)*OCH + o)*CCH + c], wt*f10);
  if (ih+1 < KS && iw+1 < KS) atomicAdd(&kf[(((ih+1)*KS + iw+1)*OCH + o)*CCH + c], wt*f11);
}

__global__ void cvt_kern(const float* __restrict__ kf, unsigned short* __restrict__ kb) {
  int i = blockIdx.x * 256 + threadIdx.x;
  if (i < KTOT) kb[i] = f2bf(kf[i]);
}

// Conv: block = (n, 4 h-rows). 4 waves; wave = one h-row, tile M=128(o) x N=64(w).
// K = 49 taps x 128 c, c chunked by 32. 16x16x32 bf16 MFMA, fp32 accum.
__global__ __launch_bounds__(256, 2) void dcls_conv(
    const float* __restrict__ x, const unsigned short* __restrict__ kb,
    const float* __restrict__ bias, float* __restrict__ out)
{
  __shared__ unsigned short xs[ROWS*WP*CCK];  // 46080 B, [r][w'][c32], chunk-swizzled
  __shared__ unsigned short as_[OCH*CCK];     //  8192 B, [o][c32], chunk-swizzled

  const int n   = blockIdx.x;
  const int hb  = blockIdx.y;
  const int tid = threadIdx.x;
  const int lane = tid & 63;
  const int wv   = tid >> 6;

  { // zero-fill xs once (pads + invalid rows stay zero for all cc passes)
    const uint4 z4 = {0u,0u,0u,0u};
    for (int i = tid; i < ROWS*WP*CCK/8; i += 256)
      *(uint4*)&xs[i*8] = z4;
  }

  v4f acc[8][4];
  #pragma unroll
  for (int m = 0; m < 8; ++m)
    #pragma unroll
    for (int t = 0; t < 4; ++t)
      acc[m][t] = (v4f){0.f,0.f,0.f,0.f};

  const int col  = lane & 15;
  const int kgrp = lane >> 4;

  for (int cc = 0; cc < 4; ++cc) {
    __syncthreads();   // xs safe to overwrite (also covers zero-fill on cc=0)
    // ---- stage x rows: transpose to [r][w'][c], f32->bf16, XOR-swizzled chunks ----
    {
      const int slot = tid & 15;       // float4 slot along w (0..13 active)
      const int pg   = tid >> 4;
      if (slot < 14) {
        for (int it = 0; it < 20; ++it) {
          const int p = pg + it*16;    // 0..319 = (r,c) pair
          const int r = p % ROWS;
          const int c = p / ROWS;
          const int hr = hb*HBLK - 3 + r;
          if ((unsigned)hr < (unsigned)HW) {
            const float4 v = *(const float4*)&x[((n*CCH + cc*CCK + c)*HW + hr)*HW + slot*4];
            const float vv[4] = {v.x, v.y, v.z, v.w};
            #pragma unroll
            for (int i = 0; i < 4; ++i) {
              const int wp = slot*4 + i + PAD;
              const int phys = (r*WP + wp)*CCK + (((c>>3) ^ ((wp>>1)&3))<<3) + (c&7);
              xs[phys] = f2bf(vv[i]);
            }
          }
        }
      }
    }
    // ---- taps ----
    for (int kh = 0; kh < KS; ++kh) {
      const int r = wv + kh;           // staged row for this wave's h-row
      for (int kw = 0; kw < KS; ++kw) {
        __syncthreads();               // as_ safe to overwrite
        { // stage A tile kb[kh*7+kw][0:128][cc*32..+32] -> as_, swizzled source chunk
          const int khkw = kh*KS + kw;
          #pragma unroll
          for (int j = 0; j < 2; ++j) {
            const int q = tid + j*256;          // 16B chunk id 0..511
            const int o = q >> 2;
            const int pc = q & 3;
            const int sc = pc ^ ((o>>1)&3);
            const uint4 av = *(const uint4*)&kb[(khkw*OCH + o)*CCH + cc*CCK + sc*8];
            *(uint4*)&as_[o*CCK + pc*8] = av;
          }
        }
        __syncthreads();
        // compute: 8 A-frags + 4 B-frags -> 32 MFMAs
        v8s a[8];
        #pragma unroll
        for (int mt = 0; mt < 8; ++mt) {
          const int o = mt*16 + col;
          a[mt] = *(const v8s*)&as_[o*CCK + ((kgrp ^ ((o>>1)&3))<<3)];
        }
        #pragma unroll
        for (int nt = 0; nt < 4; ++nt) {
          const int wp = nt*16 + col + kw;
          const v8s b = *(const v8s*)&xs[(r*WP + wp)*CCK + ((kgrp ^ ((wp>>1)&3))<<3)];
          #pragma unroll
          for (int mt = 0; mt < 8; ++mt)
            acc[mt][nt] = __builtin_amdgcn_mfma_f32_16x16x32_bf16(a[mt], b, acc[mt][nt], 0, 0, 0);
        }
      }
    }
  }
  // ---- epilogue: D row=(lane>>4)*4+reg, col=lane&15 ----
  const int h = hb*HBLK + wv;
  #pragma unroll
  for (int mt = 0; mt < 8; ++mt) {
    #pragma unroll
    for (int rr = 0; rr < 4; ++rr) {
      const int o = mt*16 + (lane>>4)*4 + rr;
      const float bs = bias[o];
      #pragma unroll
      for (int nt = 0; nt < 4; ++nt) {
        const int w = nt*16 + col;
        if (w < HW)
          out[((n*OCH + o)*HW + h)*HW + w] = acc[mt][nt][rr] + bs;
      }
    }
  }
}

extern "C" void kernel_launch(void* const* d_in, const int* in_sizes, int n_in,
                              void* d_out, int out_size, void* d_ws, size_t ws_size,
                              hipStream_t stream) {
  const float* x    = (const float*)d_in[0];
  const float* wgt  = (const float*)d_in[1];
  const float* P    = (const float*)d_in[2];
  const float* bias = (const float*)d_in[3];
  float* out = (float*)d_out;
  float* kf = (float*)d_ws;                                        // 3.2 MB fp32 dense kernel
  unsigned short* kb = (unsigned short*)((char*)d_ws + (size_t)KTOT*4); // 1.6 MB bf16 copy

  zero_kf<<<KTOT/256, 256, 0, stream>>>(kf);
  scatter_kern<<<dim3(CCH, KPTS), OCH, 0, stream>>>(wgt, P, kf);
  cvt_kern<<<KTOT/256, 256, 0, stream>>>(kf, kb);
  dcls_conv<<<dim3(NB, HW/HBLK), 256, 0, stream>>>(x, kb, bias, out);
}

// Round 2
// 209.370 us; speedup vs baseline: 1.0616x; 1.0616x over previous
//
#include <hip/hip_runtime.h>
#include <stdint.h>

typedef short v8s __attribute__((ext_vector_type(8)));
typedef float v4f __attribute__((ext_vector_type(4)));

#define KS    7
#define KPTS  9
#define OCH   128
#define CCH   128
#define NB    32
#define HW    56
#define PAD   3
#define KTOT  (KS*KS*OCH*CCH)   // 802816

#define HBLK  4
#define ROWS  10     // HBLK + 6
#define WP    72     // padded w' extent (wp reaches 69)
#define CCK   32     // c chunk staged per pass
#define NCC   4
#define HP    62     // padded h' extent (56 + 6)
#define ROWB  (WP*CCK*2)        // 4608 B per padded x_t row
#define XTSZ  ((size_t)NB*NCC*HP*WP*CCK)  // ushort elements

__device__ __forceinline__ unsigned short f2bf(float f) {
  unsigned int u = __builtin_bit_cast(unsigned int, f);
  u += 0x7fffu + ((u >> 16) & 1u);
  return (unsigned short)(u >> 16);
}

__device__ __forceinline__ void gl_lds16(const void* g, void* l) {
  __builtin_amdgcn_global_load_lds(
      (const __attribute__((address_space(1))) unsigned int*)g,
      (__attribute__((address_space(3))) unsigned int*)l, 16, 0, 0);
}

__global__ void zero_kf(float* kf) {
  int i = blockIdx.x * 256 + threadIdx.x;
  if (i < KTOT) kf[i] = 0.f;
}

// One block per (c, k-point); 128 threads = o. Bilinear scatter-add with drop.
__global__ void scatter_kern(const float* __restrict__ wgt,
                             const float* __restrict__ P,
                             float* __restrict__ kf) {
  const int c = blockIdx.x, k = blockIdx.y, o = threadIdx.x;
  const float p0 = P[c*KPTS + k];
  const float p1 = P[CCH*KPTS + c*KPTS + k];
  const float ph = fminf(fmaxf(p0, -3.f), 3.f) + 3.f;
  const float pw = fminf(fmaxf(p1, -3.f), 3.f) + 3.f;
  const int ih = (int)floorf(ph), iw = (int)floorf(pw);
  const float rh = ph - (float)ih, rw = pw - (float)iw;
  const float wt = wgt[(o*CCH + c)*KPTS + k];
  const float f00 = (1.f-rh)*(1.f-rw);
  const float f01 = (1.f-rh)*rw;
  const float f10 = rh*(1.f-rw);
  const float f11 = rh*rw;
  atomicAdd(&kf[((ih*KS + iw)*OCH + o)*CCH + c], wt*f00);
  if (iw+1 < KS) atomicAdd(&kf[((ih*KS + iw+1)*OCH + o)*CCH + c], wt*f01);
  if (ih+1 < KS) atomicAdd(&kf[(((ih+1)*KS + iw)*OCH + o)*CCH + c], wt*f10);
  if (ih+1 < KS && iw+1 < KS) atomicAdd(&kf[(((ih+1)*KS + iw+1)*OCH + o)*CCH + c], wt*f11);
}

// kf [khkw][o][c128] -> kb [cc][khkw][o][c32], A-swizzle baked (chunk ^ ((o>>1)&3))
__global__ void cvt_kern(const float* __restrict__ kf, unsigned short* __restrict__ kb) {
  int i = blockIdx.x * 256 + threadIdx.x;
  if (i >= KTOT) return;
  const int c    = i & 127;
  const int o    = (i >> 7) & 127;
  const int khkw = i >> 14;
  const int cc = c >> 5, sc = (c >> 3) & 3, cl = c & 7;
  const int pc = sc ^ ((o >> 1) & 3);
  kb[(((size_t)(cc*49 + khkw)*OCH + o)*CCK) + pc*8 + cl] = f2bf(kf[i]);
}

// x [n][c][h][w] f32 -> x_t [n][cc][h'][w'][c32] bf16, pads baked as zeros,
// B-swizzle baked: data chunk s stored at phys chunk s ^ ((w'>>1)&3).
__global__ __launch_bounds__(256) void xpose(const float* __restrict__ x,
                                             unsigned short* __restrict__ xt) {
  __shared__ unsigned short lb[CCK][HW + 2];
  const int hp = blockIdx.x;   // 0..61
  const int cc = blockIdx.y;
  const int n  = blockIdx.z;
  const int t  = threadIdx.x;
  const int h  = hp - PAD;
  const bool valid = (unsigned)h < (unsigned)HW;
  if (valid) {
    const float* xb = x + ((size_t)(n*CCH + cc*CCK)*HW + h)*HW;
    #pragma unroll
    for (int k = 0; k < 7; ++k) {
      const int j = k*256 + t;          // 0..1791
      const int c = j / HW, w = j % HW;
      lb[c][w] = f2bf(xb[(size_t)c*HW*HW + w]);
    }
  }
  __syncthreads();
  unsigned short* orow = xt + (size_t)((n*NCC + cc)*HP + hp)*(WP*CCK);
  for (int q = t; q < WP*4; q += 256) {  // 288 chunks of 8 ushorts
    const int wq = q >> 2, pc = q & 3;
    const int s  = pc ^ ((wq >> 1) & 3);
    v8s v = (v8s){0,0,0,0,0,0,0,0};
    const int w = wq - PAD;
    if (valid && (unsigned)w < (unsigned)HW) {
      #pragma unroll
      for (int jj = 0; jj < 8; ++jj) v[jj] = (short)lb[s*8 + jj][w];
    }
    *(v8s*)&orow[wq*CCK + pc*8] = v;
  }
}

// Conv: block = (n, 4 h-rows). 4 waves; wave = one h-row, tile M=128(o) x N=64(w).
// xs staged per cc via linear global_load_lds; A double-buffered + prefetched.
__global__ __launch_bounds__(256, 2) void dcls_conv(
    const unsigned short* __restrict__ xt, const unsigned short* __restrict__ kb,
    const float* __restrict__ bias, float* __restrict__ out)
{
  __shared__ unsigned short xs[ROWS*WP*CCK];   // 46080 B
  __shared__ unsigned short as_[2][OCH*CCK];   // 2 x 8192 B  (total 62464 B)

  const int n   = blockIdx.x;
  const int hb  = blockIdx.y;
  const int tid = threadIdx.x;
  const int lane = tid & 63;
  const int wv   = tid >> 6;
  const int col  = lane & 15;
  const int kgrp = lane >> 4;

  v4f acc[8][4];
  #pragma unroll
  for (int m = 0; m < 8; ++m)
    #pragma unroll
    for (int t = 0; t < 4; ++t)
      acc[m][t] = (v4f){0.f,0.f,0.f,0.f};

  for (int cc = 0; cc < NCC; ++cc) {
    // ---- stage xs: one contiguous 45 KB span of x_t, pure linear copy ----
    const char* src = (const char*)xt + (size_t)((n*NCC + cc)*HP + hb*HBLK)*ROWB;
    for (int i = wv; i < 45; i += 4)
      gl_lds16(src + i*1024 + lane*16, (char*)xs + i*1024);
    // ---- stage A(0) into buf 0 ----
    const char* ks = (const char*)kb + (size_t)cc*49*8192;
    #pragma unroll
    for (int j = 0; j < 2; ++j)
      gl_lds16(ks + wv*2048 + j*1024 + lane*16, (char*)as_[0] + wv*2048 + j*1024);
    __syncthreads();   // drains vmcnt: xs + A(0) resident

    int tap = 0;
    for (int kh = 0; kh < KS; ++kh) {
      const int r = wv + kh;
      for (int kw = 0; kw < KS; ++kw, ++tap) {
        const int cur = tap & 1;
        if (tap < 48) {  // prefetch next A tile into the other buffer
          #pragma unroll
          for (int j = 0; j < 2; ++j)
            gl_lds16(ks + (size_t)(tap+1)*8192 + wv*2048 + j*1024 + lane*16,
                     (char*)as_[cur ^ 1] + wv*2048 + j*1024);
        }
        v8s a[8];
        #pragma unroll
        for (int mt = 0; mt < 8; ++mt) {
          const int o = mt*16 + col;
          a[mt] = *(const v8s*)&as_[cur][o*CCK + ((kgrp ^ ((o >> 1) & 3)) << 3)];
        }
        #pragma unroll
        for (int nt = 0; nt < 4; ++nt) {
          const int wp = nt*16 + col + kw;
          const v8s b = *(const v8s*)&xs[(r*WP + wp)*CCK + ((kgrp ^ ((wp >> 1) & 3)) << 3)];
          #pragma unroll
          for (int mt = 0; mt < 8; ++mt)
            acc[mt][nt] = __builtin_amdgcn_mfma_f32_16x16x32_bf16(a[mt], b, acc[mt][nt], 0, 0, 0);
        }
        __syncthreads();  // drains prefetch; buffers safe to swap/overwrite
      }
    }
  }

  // ---- epilogue: D row=(lane>>4)*4+reg, col=lane&15 ----
  const int h = hb*HBLK + wv;
  #pragma unroll
  for (int mt = 0; mt < 8; ++mt) {
    #pragma unroll
    for (int rr = 0; rr < 4; ++rr) {
      const int o = mt*16 + (lane >> 4)*4 + rr;
      const float bs = bias[o];
      #pragma unroll
      for (int nt = 0; nt < 4; ++nt) {
        const int w = nt*16 + col;
        if (w < HW)
          out[((size_t)(n*OCH + o)*HW + h)*HW + w] = acc[mt][nt][rr] + bs;
      }
    }
  }
}

extern "C" void kernel_launch(void* const* d_in, const int* in_sizes, int n_in,
                              void* d_out, int out_size, void* d_ws, size_t ws_size,
                              hipStream_t stream) {
  const float* x    = (const float*)d_in[0];
  const float* wgt  = (const float*)d_in[1];
  const float* P    = (const float*)d_in[2];
  const float* bias = (const float*)d_in[3];
  float* out = (float*)d_out;

  float*          kf = (float*)d_ws;                                   // 3.2 MB
  unsigned short* kb = (unsigned short*)((char*)d_ws + (size_t)KTOT*4); // 1.6 MB
  unsigned short* xt = (unsigned short*)((char*)d_ws + (size_t)KTOT*6); // 36.6 MB

  zero_kf<<<KTOT/256, 256, 0, stream>>>(kf);
  scatter_kern<<<dim3(CCH, KPTS), OCH, 0, stream>>>(wgt, P, kf);
  cvt_kern<<<KTOT/256, 256, 0, stream>>>(kf, kb);
  xpose<<<dim3(HP, NCC, NB), 256, 0, stream>>>(x, xt);
  dcls_conv<<<dim3(NB, HW/HBLK), 256, 0, stream>>>(xt, kb, bias, out);
}

// Round 3
// 197.568 us; speedup vs baseline: 1.1250x; 1.0597x over previous
//
#include <hip/hip_runtime.h>
#include <stdint.h>

typedef short v8s __attribute__((ext_vector_type(8)));
typedef float v4f __attribute__((ext_vector_type(4)));

#define KS    7
#define KPTS  9
#define OCH   128
#define CCH   128
#define NB    32
#define HW    56
#define PAD   3
#define KTOT  (KS*KS*OCH*CCH)   // 802816

#define HBLK  4
#define ROWS  10     // HBLK + 6
#define WP    72     // padded w' extent
#define CCK   32     // c chunk staged per pass
#define NCC   4
#define HP    62     // padded h' extent
#define ROWB  (WP*CCK*2)        // 4608 B per padded x_t row
#define XS_B  (ROWS*WP*CCK*2)   // 46080 B
#define AB_B  (4*OCH*CCK*2)     // 32768 B (4 A-buffers)
#define SMEM_B (XS_B + AB_B)    // 78848 B

__device__ __forceinline__ unsigned short f2bf(float f) {
  unsigned int u = __builtin_bit_cast(unsigned int, f);
  u += 0x7fffu + ((u >> 16) & 1u);
  return (unsigned short)(u >> 16);
}

__device__ __forceinline__ void gl_lds16(const void* g, void* l) {
  __builtin_amdgcn_global_load_lds(
      (const __attribute__((address_space(1))) unsigned int*)g,
      (__attribute__((address_space(3))) unsigned int*)l, 16, 0, 0);
}

// One block per (c, k-point); 128 threads = o. Bilinear scatter-add with drop.
__global__ void scatter_kern(const float* __restrict__ wgt,
                             const float* __restrict__ P,
                             float* __restrict__ kf) {
  const int c = blockIdx.x, k = blockIdx.y, o = threadIdx.x;
  const float p0 = P[c*KPTS + k];
  const float p1 = P[CCH*KPTS + c*KPTS + k];
  const float ph = fminf(fmaxf(p0, -3.f), 3.f) + 3.f;
  const float pw = fminf(fmaxf(p1, -3.f), 3.f) + 3.f;
  const int ih = (int)floorf(ph), iw = (int)floorf(pw);
  const float rh = ph - (float)ih, rw = pw - (float)iw;
  const float wt = wgt[(o*CCH + c)*KPTS + k];
  const float f00 = (1.f-rh)*(1.f-rw);
  const float f01 = (1.f-rh)*rw;
  const float f10 = rh*(1.f-rw);
  const float f11 = rh*rw;
  atomicAdd(&kf[((ih*KS + iw)*OCH + o)*CCH + c], wt*f00);
  if (iw+1 < KS) atomicAdd(&kf[((ih*KS + iw+1)*OCH + o)*CCH + c], wt*f01);
  if (ih+1 < KS) atomicAdd(&kf[(((ih+1)*KS + iw)*OCH + o)*CCH + c], wt*f10);
  if (ih+1 < KS && iw+1 < KS) atomicAdd(&kf[(((ih+1)*KS + iw+1)*OCH + o)*CCH + c], wt*f11);
}

// kf [khkw][o][c128] -> kb [cc][khkw][o][c32], A-swizzle baked (chunk ^ ((o>>1)&3))
__global__ void cvt_kern(const float* __restrict__ kf, unsigned short* __restrict__ kb) {
  int i = blockIdx.x * 256 + threadIdx.x;
  if (i >= KTOT) return;
  const int c    = i & 127;
  const int o    = (i >> 7) & 127;
  const int khkw = i >> 14;
  const int cc = c >> 5, sc = (c >> 3) & 3, cl = c & 7;
  const int pc = sc ^ ((o >> 1) & 3);
  kb[(((size_t)(cc*49 + khkw)*OCH + o)*CCK) + pc*8 + cl] = f2bf(kf[i]);
}

// x [n][c][h][w] f32 -> x_t [n][cc][h'][w'][c32] bf16, pads baked as zeros,
// B-swizzle baked: data chunk s stored at phys chunk s ^ ((w'>>1)&3).
__global__ __launch_bounds__(256) void xpose(const float* __restrict__ x,
                                             unsigned short* __restrict__ xt) {
  __shared__ unsigned short lb[CCK][HW + 2];
  const int hp = blockIdx.x;   // 0..61
  const int cc = blockIdx.y;
  const int n  = blockIdx.z;
  const int t  = threadIdx.x;
  const int h  = hp - PAD;
  const bool valid = (unsigned)h < (unsigned)HW;
  if (valid) {
    const float* xb = x + ((size_t)(n*CCH + cc*CCK)*HW + h)*HW;
    #pragma unroll
    for (int k = 0; k < 7; ++k) {
      const int j = k*256 + t;          // 0..1791
      const int c = j / HW, w = j % HW;
      lb[c][w] = f2bf(xb[(size_t)c*HW*HW + w]);
    }
  }
  __syncthreads();
  unsigned short* orow = xt + (size_t)((n*NCC + cc)*HP + hp)*(WP*CCK);
  for (int q = t; q < WP*4; q += 256) {  // 288 chunks of 8 ushorts
    const int wq = q >> 2, pc = q & 3;
    const int s  = pc ^ ((wq >> 1) & 3);
    v8s v = (v8s){0,0,0,0,0,0,0,0};
    const int w = wq - PAD;
    if (valid && (unsigned)w < (unsigned)HW) {
      #pragma unroll
      for (int jj = 0; jj < 8; ++jj) v[jj] = (short)lb[s*8 + jj][w];
    }
    *(v8s*)&orow[wq*CCK + pc*8] = v;
  }
}

// Conv: block = (n, 4 h-rows). 4 waves; wave = one h-row, tile M=128(o) x N=64(w).
// 2-tap phases, 4 A-buffers (pairs ping-pong), one barrier per phase, setprio
// around the MFMA cluster. Dynamic LDS 78848 B -> still 2 blocks/CU.
__global__ __launch_bounds__(256, 2) void dcls_conv(
    const unsigned short* __restrict__ xt, const unsigned short* __restrict__ kb,
    const float* __restrict__ bias, float* __restrict__ out)
{
  extern __shared__ char smem[];
  unsigned short* xs = (unsigned short*)smem;            // [ROWS][WP][CCK]
  unsigned short* ab = (unsigned short*)(smem + XS_B);   // 4 bufs of [OCH][CCK]

  const int n   = blockIdx.x;
  const int hb  = blockIdx.y;
  const int tid = threadIdx.x;
  const int lane = tid & 63;
  const int wv   = tid >> 6;
  const int col  = lane & 15;
  const int kgrp = lane >> 4;

  v4f acc[8][4];
  #pragma unroll
  for (int m = 0; m < 8; ++m)
    #pragma unroll
    for (int t = 0; t < 4; ++t)
      acc[m][t] = (v4f){0.f,0.f,0.f,0.f};

  for (int cc = 0; cc < NCC; ++cc) {
    // ---- stage xs: one contiguous 45 KB span of x_t, pure linear copy ----
    const char* src = (const char*)xt + (size_t)((n*NCC + cc)*HP + hb*HBLK)*ROWB;
    for (int i = wv; i < 45; i += 4)
      gl_lds16(src + i*1024 + lane*16, (char*)xs + i*1024);
    // ---- stage A tiles 0,1 into bufs 0,1 ----
    const char* ks = (const char*)kb + (size_t)cc*49*8192;
    #pragma unroll
    for (int u = 0; u < 2; ++u)
      #pragma unroll
      for (int j = 0; j < 2; ++j)
        gl_lds16(ks + u*8192 + wv*2048 + j*1024 + lane*16,
                 (char*)ab + u*8192 + wv*2048 + j*1024);
    __syncthreads();   // xs + A0 + A1 resident

    for (int ph = 0; ph < 25; ++ph) {
      const int t0 = 2*ph;
      // prefetch taps t0+2, t0+3 into the buffer pair freed last phase
      #pragma unroll
      for (int u = 2; u < 4; ++u) {
        const int t = t0 + u;
        if (t < 49) {
          #pragma unroll
          for (int j = 0; j < 2; ++j)
            gl_lds16(ks + (size_t)t*8192 + wv*2048 + j*1024 + lane*16,
                     (char*)ab + (size_t)(t & 3)*8192 + wv*2048 + j*1024);
        }
      }
      // compute taps t0, t0+1 (no barrier between -> cross-tap pipelining)
      #pragma unroll
      for (int u = 0; u < 2; ++u) {
        const int t = t0 + u;
        if (t < 49) {
          const int kh = t / 7, kw = t - kh*7;
          const int r = wv + kh;
          const unsigned short* abuf = ab + (size_t)(t & 3)*(OCH*CCK);
          v8s a[8];
          #pragma unroll
          for (int mt = 0; mt < 8; ++mt) {
            const int o = mt*16 + col;
            a[mt] = *(const v8s*)&abuf[o*CCK + ((kgrp ^ ((o >> 1) & 3)) << 3)];
          }
          __builtin_amdgcn_s_setprio(1);
          #pragma unroll
          for (int nt = 0; nt < 4; ++nt) {
            const int wp = nt*16 + col + kw;
            const v8s b = *(const v8s*)&xs[(r*WP + wp)*CCK + ((kgrp ^ ((wp >> 1) & 3)) << 3)];
            #pragma unroll
            for (int mt = 0; mt < 8; ++mt)
              acc[mt][nt] = __builtin_amdgcn_mfma_f32_16x16x32_bf16(a[mt], b, acc[mt][nt], 0, 0, 0);
          }
          __builtin_amdgcn_s_setprio(0);
        }
      }
      __syncthreads();  // prefetched pair resident; compute pair free next phase
    }
  }

  // ---- epilogue: D row=(lane>>4)*4+reg, col=lane&15 ----
  const int h = hb*HBLK + wv;
  #pragma unroll
  for (int mt = 0; mt < 8; ++mt) {
    #pragma unroll
    for (int rr = 0; rr < 4; ++rr) {
      const int o = mt*16 + (lane >> 4)*4 + rr;
      const float bs = bias[o];
      #pragma unroll
      for (int nt = 0; nt < 4; ++nt) {
        const int w = nt*16 + col;
        if (w < HW)
          out[((size_t)(n*OCH + o)*HW + h)*HW + w] = acc[mt][nt][rr] + bs;
      }
    }
  }
}

extern "C" void kernel_launch(void* const* d_in, const int* in_sizes, int n_in,
                              void* d_out, int out_size, void* d_ws, size_t ws_size,
                              hipStream_t stream) {
  const float* x    = (const float*)d_in[0];
  const float* wgt  = (const float*)d_in[1];
  const float* P    = (const float*)d_in[2];
  const float* bias = (const float*)d_in[3];
  float* out = (float*)d_out;

  float*          kf = (float*)d_ws;                                    // 3.2 MB
  unsigned short* kb = (unsigned short*)((char*)d_ws + (size_t)KTOT*4); // 1.6 MB
  unsigned short* xt = (unsigned short*)((char*)d_ws + (size_t)KTOT*6); // 36.6 MB

  hipFuncSetAttribute((const void*)dcls_conv,
                      hipFuncAttributeMaxDynamicSharedMemorySize, SMEM_B);

  hipMemsetAsync(kf, 0, (size_t)KTOT*4, stream);
  scatter_kern<<<dim3(CCH, KPTS), OCH, 0, stream>>>(wgt, P, kf);
  cvt_kern<<<KTOT/256, 256, 0, stream>>>(kf, kb);
  xpose<<<dim3(HP, NCC, NB), 256, 0, stream>>>(x, xt);
  dcls_conv<<<dim3(NB, HW/HBLK), 256, SMEM_B, stream>>>(xt, kb, bias, out);
}

// Round 4
// 159.335 us; speedup vs baseline: 1.3949x; 1.2400x over previous
//
#include <hip/hip_runtime.h>
#include <stdint.h>

typedef short v8s __attribute__((ext_vector_type(8)));
typedef float v4f __attribute__((ext_vector_type(4)));

#define KS    7
#define KPTS  9
#define OCH   128
#define CCH   128
#define NB    32
#define HW    56
#define PAD   3

#define HBLK  4
#define ROWS  10
#define WP    72
#define CCK   32
#define NCC   4
#define HP    62
#define ROWB  (WP*CCK*2)        // 4608 B per padded x_t row
#define XS_B  (ROWS*WP*CCK*2)   // 46080 B
#define AB_B  (4*OCH*CCK*2)     // 32768 B (4 A-buffers)
#define SMEM_B (XS_B + AB_B)    // 78848 B
#define KB_BYTES ((size_t)NCC*49*OCH*CCK*2)

__device__ __forceinline__ unsigned short f2bf(float f) {
  unsigned int u = __builtin_bit_cast(unsigned int, f);
  u += 0x7fffu + ((u >> 16) & 1u);
  return (unsigned short)(u >> 16);
}

__device__ __forceinline__ void gl_lds16(const void* g, void* l) {
  __builtin_amdgcn_global_load_lds(
      (const __attribute__((address_space(1))) unsigned int*)g,
      (__attribute__((address_space(3))) unsigned int*)l, 16, 0, 0);
}

// Fused kernel construction: block = c (128 blocks), thread = o (128).
// Per-thread private 49-float row in LDS -> no atomics, no zero/cvt passes.
// Output kb [cc][tap][o][c32] bf16, A-swizzle baked (chunk ^ ((o>>1)&3)).
__global__ __launch_bounds__(128) void build_kern(
    const float* __restrict__ wgt, const float* __restrict__ P,
    unsigned short* __restrict__ kb) {
  __shared__ float sm[OCH*49];
  const int c = blockIdx.x, o = threadIdx.x;
  float* mine = &sm[o*49];
  #pragma unroll
  for (int j = 0; j < 49; ++j) mine[j] = 0.f;
  for (int k = 0; k < KPTS; ++k) {
    const float ph = fminf(fmaxf(P[c*KPTS + k], -3.f), 3.f) + 3.f;
    const float pw = fminf(fmaxf(P[CCH*KPTS + c*KPTS + k], -3.f), 3.f) + 3.f;
    const int ih = (int)floorf(ph), iw = (int)floorf(pw);
    const float rh = ph - (float)ih, rw = pw - (float)iw;
    const float wt = wgt[(o*CCH + c)*KPTS + k];
    mine[ih*KS + iw] += wt*(1.f-rh)*(1.f-rw);
    if (iw+1 < KS) mine[ih*KS + iw+1] += wt*(1.f-rh)*rw;
    if (ih+1 < KS) mine[(ih+1)*KS + iw] += wt*rh*(1.f-rw);
    if (ih+1 < KS && iw+1 < KS) mine[(ih+1)*KS + iw+1] += wt*rh*rw;
  }
  const int cc = c >> 5, sc = (c >> 3) & 3, cl = c & 7;
  const int pc = sc ^ ((o >> 1) & 3);
  for (int tap = 0; tap < 49; ++tap)
    kb[(((size_t)(cc*49 + tap)*OCH + o)*CCK) + pc*8 + cl] = f2bf(mine[tap]);
}

// x [n][c][h][w] f32 -> x_t [n][cc][h'][w'][c32] bf16, pads baked as zeros,
// B-swizzle baked: data chunk s stored at phys chunk s ^ ((w'>>1)&3).
__global__ __launch_bounds__(256) void xpose(const float* __restrict__ x,
                                             unsigned short* __restrict__ xt) {
  __shared__ unsigned short lb[CCK][HW + 2];
  const int hp = blockIdx.x;
  const int cc = blockIdx.y;
  const int n  = blockIdx.z;
  const int t  = threadIdx.x;
  const int h  = hp - PAD;
  const bool valid = (unsigned)h < (unsigned)HW;
  if (valid) {
    const float* xb = x + ((size_t)(n*CCH + cc*CCK)*HW + h)*HW;
    #pragma unroll
    for (int k = 0; k < 7; ++k) {
      const int j = k*256 + t;
      const int c = j / HW, w = j % HW;
      lb[c][w] = f2bf(xb[(size_t)c*HW*HW + w]);
    }
  }
  __syncthreads();
  unsigned short* orow = xt + (size_t)((n*NCC + cc)*HP + hp)*(WP*CCK);
  for (int q = t; q < WP*4; q += 256) {
    const int wq = q >> 2, pc = q & 3;
    const int s  = pc ^ ((wq >> 1) & 3);
    v8s v = (v8s){0,0,0,0,0,0,0,0};
    const int w = wq - PAD;
    if (valid && (unsigned)w < (unsigned)HW) {
      #pragma unroll
      for (int jj = 0; jj < 8; ++jj) v[jj] = (short)lb[s*8 + jj][w];
    }
    *(v8s*)&orow[wq*CCK + pc*8] = v;
  }
}

#define MFMA_TAP(FA, FB)                                                      \
  __builtin_amdgcn_s_setprio(1);                                              \
  _Pragma("unroll")                                                           \
  for (int nt = 0; nt < 4; ++nt) {                                            \
    _Pragma("unroll")                                                         \
    for (int mt = 0; mt < 8; ++mt)                                            \
      acc[mt][nt] = __builtin_amdgcn_mfma_f32_16x16x32_bf16(FA[mt], FB[nt],   \
                                                            acc[mt][nt], 0, 0, 0); \
  }                                                                           \
  __builtin_amdgcn_s_setprio(0);

// Conv: block = (n, 4 h-rows). 4 waves; wave = one h-row, M=128(o) x N=64(w).
// Register double-buffered fragments: frags(t+1) read under MFMA(t);
// B(t+2) read pre-barrier (xs static); only A(t+2) read exposed post-barrier.
__global__ __launch_bounds__(256, 2) void dcls_conv(
    const unsigned short* __restrict__ xt, const unsigned short* __restrict__ kb,
    const float* __restrict__ bias, float* __restrict__ out)
{
  extern __shared__ char smem[];
  unsigned short* xs = (unsigned short*)smem;            // [ROWS][WP][CCK]
  unsigned short* ab = (unsigned short*)(smem + XS_B);   // 4 bufs of [OCH][CCK]

  const int n   = blockIdx.x;
  const int hb  = blockIdx.y;
  const int tid = threadIdx.x;
  const int lane = tid & 63;
  const int wv   = tid >> 6;
  const int col  = lane & 15;
  const int kgrp = lane >> 4;
  const int swA  = (kgrp ^ ((col >> 1) & 3)) << 3;

  v4f acc[8][4];
  #pragma unroll
  for (int m = 0; m < 8; ++m)
    #pragma unroll
    for (int t = 0; t < 4; ++t)
      acc[m][t] = (v4f){0.f,0.f,0.f,0.f};

  v8s fa0[8], fa1[8], fb0[4], fb1[4];

  for (int cc = 0; cc < NCC; ++cc) {
    // ---- stage xs (linear 45 KB) + A(0),A(1) ----
    const char* src = (const char*)xt + (size_t)((n*NCC + cc)*HP + hb*HBLK)*ROWB;
    for (int i = wv; i < 45; i += 4)
      gl_lds16(src + i*1024 + lane*16, (char*)xs + i*1024);
    const char* ks = (const char*)kb + (size_t)cc*49*8192;
    #pragma unroll
    for (int u = 0; u < 2; ++u)
      #pragma unroll
      for (int j = 0; j < 2; ++j)
        gl_lds16(ks + u*8192 + wv*2048 + j*1024 + lane*16,
                 (char*)ab + u*8192 + wv*2048 + j*1024);
    __syncthreads();

    // ---- tap-0 fragments ----
    #pragma unroll
    for (int mt = 0; mt < 8; ++mt)
      fa0[mt] = *(const v8s*)&ab[(mt*16 + col)*CCK + swA];
    {
      const int swB = (kgrp ^ ((col >> 1) & 3)) << 3;     // kw = 0
      const int base = (wv*WP + col)*CCK + swB;
      #pragma unroll
      for (int nt = 0; nt < 4; ++nt)
        fb0[nt] = *(const v8s*)&xs[base + nt*512];
    }

    for (int phx = 0; phx < 24; ++phx) {
      const int t0 = 2*phx;
      // ---- prefetch A(t0+2), A(t0+3) ----
      {
        const int tp = t0 + 2;
        #pragma unroll
        for (int j = 0; j < 2; ++j)
          gl_lds16(ks + (size_t)tp*8192 + wv*2048 + j*1024 + lane*16,
                   (char*)ab + (size_t)(tp & 3)*8192 + wv*2048 + j*1024);
        const int tq = t0 + 3;
        if (tq < 49) {
          #pragma unroll
          for (int j = 0; j < 2; ++j)
            gl_lds16(ks + (size_t)tq*8192 + wv*2048 + j*1024 + lane*16,
                     (char*)ab + (size_t)(tq & 3)*8192 + wv*2048 + j*1024);
        }
      }
      // ---- frags(t0+1) under MFMA(t0) ----
      {
        const int t = t0 + 1, kh = t/7, kw = t - kh*7, r = wv + kh;
        const unsigned short* ap = ab + (size_t)(t & 3)*(OCH*CCK);
        #pragma unroll
        for (int mt = 0; mt < 8; ++mt)
          fa1[mt] = *(const v8s*)&ap[(mt*16 + col)*CCK + swA];
        const int swB = (kgrp ^ (((col + kw) >> 1) & 3)) << 3;
        const int base = (r*WP + col + kw)*CCK + swB;
        #pragma unroll
        for (int nt = 0; nt < 4; ++nt)
          fb1[nt] = *(const v8s*)&xs[base + nt*512];
      }
      MFMA_TAP(fa0, fb0)
      // ---- B(t0+2) pre-barrier (xs static) under MFMA(t0+1) ----
      {
        const int t = t0 + 2, kh = t/7, kw = t - kh*7, r = wv + kh;
        const int swB = (kgrp ^ (((col + kw) >> 1) & 3)) << 3;
        const int base = (r*WP + col + kw)*CCK + swB;
        #pragma unroll
        for (int nt = 0; nt < 4; ++nt)
          fb0[nt] = *(const v8s*)&xs[base + nt*512];
      }
      MFMA_TAP(fa1, fb1)
      __syncthreads();
      // ---- A(t0+2) post-barrier (the only exposed read burst) ----
      {
        const unsigned short* ap = ab + (size_t)((t0 + 2) & 3)*(OCH*CCK);
        #pragma unroll
        for (int mt = 0; mt < 8; ++mt)
          fa0[mt] = *(const v8s*)&ap[(mt*16 + col)*CCK + swA];
      }
    }
    // ---- tap 48 ----
    MFMA_TAP(fa0, fb0)
    __syncthreads();   // protect A-buf0/xs before next cc restage
  }

  // ---- epilogue: D row=(lane>>4)*4+reg, col=lane&15 ----
  const int h = hb*HBLK + wv;
  #pragma unroll
  for (int mt = 0; mt < 8; ++mt) {
    #pragma unroll
    for (int rr = 0; rr < 4; ++rr) {
      const int o = mt*16 + (lane >> 4)*4 + rr;
      const float bs = bias[o];
      #pragma unroll
      for (int nt = 0; nt < 4; ++nt) {
        const int w = nt*16 + col;
        if (w < HW)
          out[((size_t)(n*OCH + o)*HW + h)*HW + w] = acc[mt][nt][rr] + bs;
      }
    }
  }
}

extern "C" void kernel_launch(void* const* d_in, const int* in_sizes, int n_in,
                              void* d_out, int out_size, void* d_ws, size_t ws_size,
                              hipStream_t stream) {
  const float* x    = (const float*)d_in[0];
  const float* wgt  = (const float*)d_in[1];
  const float* P    = (const float*)d_in[2];
  const float* bias = (const float*)d_in[3];
  float* out = (float*)d_out;

  unsigned short* kb = (unsigned short*)d_ws;                       // 1.6 MB
  unsigned short* xt = (unsigned short*)((char*)d_ws + (2u<<20));   // 36.6 MB

  hipFuncSetAttribute((const void*)dcls_conv,
                      hipFuncAttributeMaxDynamicSharedMemorySize, SMEM_B);

  build_kern<<<CCH, OCH, 0, stream>>>(wgt, P, kb);
  xpose<<<dim3(HP, NCC, NB), 256, 0, stream>>>(x, xt);
  dcls_conv<<<dim3(NB, HW/HBLK), 256, SMEM_B, stream>>>(xt, kb, bias, out);
}